// Round 9
// baseline (652.194 us; speedup 1.0000x reference)
//
#include <hip/hip_runtime.h>

// SDGraphUNet on MI355X — round 8.
//  k_knn: 512 threads / 8 waves per block (grid stays 512 = 2 blocks/CU).
//  Phase 2 scan splits 8 ways, phase 3 handles 8 queries/wave. 2x waves/SIMD.
//  Phase-1 thresholds still computed by waves 0-3 with identical arithmetic;
//  rank-based selection is collection-order-invariant => i50 bit-identical.
//
// ws unchanged: 63.5 MB

#define LEAKK 0.2f

typedef short s16x8 __attribute__((ext_vector_type(8)));
typedef float f32x4 __attribute__((ext_vector_type(4)));

__device__ __forceinline__ float leaky(float x){ return x > 0.f ? x : LEAKK*x; }
__device__ __forceinline__ unsigned rne_bf16(float v){
  unsigned bits = __float_as_uint(v);
  return (bits + 0x7FFFu + ((bits >> 16) & 1u)) >> 16;
}

// ---------------- prep: hi/lo splits + Wd transpose ----------------
__global__ __launch_bounds__(256) void k_prep(const float* __restrict__ W1,
                                              const float* __restrict__ W2,
                                              const float* __restrict__ Wd,
                                              unsigned short* __restrict__ w1h,
                                              unsigned short* __restrict__ w1l,
                                              unsigned short* __restrict__ w2h,
                                              unsigned short* __restrict__ w2l,
                                              float* __restrict__ wdt){
  int idx = blockIdx.x*256 + threadIdx.x;       // < 41984
  if (idx < 21504){
    int row = idx / 96, k = idx - row*96;
    float v = 0.f;
    if (row < 110) v = W1[row*192 + k];
    else if (row >= 112 && row < 222) v = W1[(row - 112)*192 + 96 + k];
    unsigned bits = __float_as_uint(v);
    w1h[idx] = (unsigned short)(bits >> 16);
    float hv = __uint_as_float(bits & 0xFFFF0000u);
    w1l[idx] = (unsigned short)rne_bf16(v - hv);
  } else if (idx < 29696){
    int j = idx - 21504;
    int row = j >> 7, k = j & 127;
    float v = (k < 110) ? W2[row*110 + k] : 0.f;
    unsigned bits = __float_as_uint(v);
    w2h[j] = (unsigned short)(bits >> 16);
    float hv = __uint_as_float(bits & 0xFFFF0000u);
    w2l[j] = (unsigned short)rne_bf16(v - hv);
  } else if (idx < 41984){
    int j = idx - 29696;                        // tt*4096 + o*64 + i
    int tt = j >> 12, rest = j & 4095, o = rest >> 6, i = rest & 63;
    wdt[j] = Wd[(o*64 + i)*3 + tt];
  }
}

// ---------------- build dense union features (fp32 + bf16) + x2 ----------------
__global__ __launch_bounds__(256) void k_build_xt(const float* __restrict__ dense,
                                                  const float* __restrict__ sparse,
                                                  float* __restrict__ xt,
                                                  unsigned short* __restrict__ xtb,
                                                  float* __restrict__ x2){
  __shared__ float D[32*65];
  __shared__ float sArr[64];
  int blk = blockIdx.x;               // ((b*32+s)*4 + q4)
  int q4 = blk & 3, bs = blk >> 2, b = bs >> 5, s = bs & 31;
  int tid = threadIdx.x;
  if (tid < 64) sArr[tid] = sparse[(b*64 + tid)*32 + s];
  for (int i = tid; i < 2048; i += 256){
    int c = i >> 6, pp = i & 63;
    D[c*65 + pp] = dense[(((b*32 + c)*32 + s) << 8) + q4*64 + pp];
  }
  __syncthreads();
  float ss = 0.f;
  #pragma unroll
  for (int ch = 0; ch < 64; ++ch){ float v = sArr[ch]; ss = __builtin_fmaf(v, v, ss); }
  size_t base = ((size_t)b*8192 + s*256 + q4*64)*96;
  for (int i = tid; i < 6144; i += 256){
    int pp = i / 96, c = i - pp*96;
    float v = (c < 32) ? D[c*65 + pp] : sArr[c - 32];
    xt[base + i] = v;
    xtb[base + i] = (unsigned short)rne_bf16(v);
  }
  if (tid < 64){
    float a = ss;
    #pragma unroll
    for (int c = 0; c < 32; ++c){ float v = D[c*65 + tid]; a = __builtin_fmaf(v, v, a); }
    x2[b*8192 + s*256 + q4*64 + tid] = a;
  }
}

// ---------------- sparse union (max over points + concat) ----------------
__global__ void k_sparse_union(const float* __restrict__ sp, const float* __restrict__ dn,
                               float* __restrict__ xtsp){
  int b = blockIdx.x >> 5, i = blockIdx.x & 31;
  int w = threadIdx.x >> 6, l = threadIdx.x & 63;
  if (w == 0) xtsp[(b*32 + i)*96 + l] = sp[(b*64 + l)*32 + i];
  for (int c = w; c < 32; c += 4){
    const float* row = dn + (((size_t)(b*32 + c)*32 + i) << 8);
    float v = fmaxf(fmaxf(row[l], row[l+64]), fmaxf(row[l+128], row[l+192]));
    for (int off = 32; off > 0; off >>= 1) v = fmaxf(v, __shfl_down(v, off));
    if (l == 0) xtsp[(b*32 + i)*96 + 64 + c] = v;
  }
}

// ---------------- sparse GCN (k=2 over 32 strokes) ----------------
__global__ void k_sparse_gcn(const float* __restrict__ xtsp,
                             const float* __restrict__ W1, const float* __restrict__ bb1,
                             const float* __restrict__ W2, const float* __restrict__ bb2,
                             float* __restrict__ outp){
  int b = blockIdx.x >> 5, i = blockIdx.x & 31, t = threadIdx.x;
  __shared__ float X[32*96];
  __shared__ float x2l[32], dd[32];
  __shared__ int nb[2];
  for (int k = t; k < 3072; k += 192) X[k] = xtsp[b*3072 + k];
  __syncthreads();
  if (t < 32){
    float s = 0.f;
    for (int c = 0; c < 96; ++c){ float v = X[t*96+c]; s += v*v; }
    x2l[t] = s;
  }
  __syncthreads();
  if (t < 32){
    float dot = 0.f;
    for (int c = 0; c < 96; ++c) dot += X[i*96+c]*X[t*96+c];
    dd[t] = x2l[i] - 2.f*dot + x2l[t];
  }
  __syncthreads();
  if (t == 0){
    int s0 = -1, s1 = -1;
    for (int j = 0; j < 32; ++j){
      float dj = dd[j];
      if (s0 < 0 || dj < dd[s0]){ s1 = s0; s0 = j; }
      else if (s1 < 0 || dj < dd[s1]){ s1 = j; }
    }
    nb[0] = s0; nb[1] = s1;
  }
  __syncthreads();
  __shared__ __align__(16) float E[192];
  __shared__ __align__(16) float H1[156];
  float acc = -3.4e38f;
  for (int n = 0; n < 2; ++n){
    int j = nb[n];
    if (t < 96){ E[t] = X[j*96+t] - X[i*96+t]; E[96+t] = X[i*96+t]; }
    __syncthreads();
    if (t < 156){
      float h = bb1[t];
      const float* wr = W1 + t*192;
      for (int k = 0; k < 192; ++k) h += E[k]*wr[k];
      H1[t] = leaky(h);
    }
    __syncthreads();
    if (t < 128){
      float h = bb2[t];
      const float* wr = W2 + t*156;
      for (int m = 0; m < 156; ++m) h += H1[m]*wr[m];
      acc = fmaxf(acc, leaky(h));
    }
    __syncthreads();
  }
  if (t < 128) outp[(b*128 + t)*32 + i] = acc;
}

// ---- 16 queries x 16 cands -> u = 256 - d_approx; shared by both kNN phases ----
__device__ __forceinline__ f32x4 score16v(s16x8 a0, s16x8 a1, s16x8 a2,
                                          s16x8 b0, s16x8 b1, s16x8 b2,
                                          float x2c, const float* x2q){
  f32x4 acc = {0.f,0.f,0.f,0.f};
  acc = __builtin_amdgcn_mfma_f32_16x16x32_bf16(a0, b0, acc, 0, 0, 0);
  acc = __builtin_amdgcn_mfma_f32_16x16x32_bf16(a1, b1, acc, 0, 0, 0);
  acc = __builtin_amdgcn_mfma_f32_16x16x32_bf16(a2, b2, acc, 0, 0, 0);
  f32x4 u;
  #pragma unroll
  for (int r = 0; r < 4; ++r)
    u[r] = (__builtin_fmaf(2.f, acc[r], -x2c) - x2q[r]) + 256.f;
  return u;
}

// ---------------- fused kNN v6 (8 waves/block) ----------------
__global__ __launch_bounds__(512) void k_knn(const unsigned short* __restrict__ xtb,
                                             const float* __restrict__ x2,
                                             const float* __restrict__ xt,
                                             int* __restrict__ i50){
  // idxL u16[64][128]:0..16384 | cnt@16384 | thrS@16640
  // rr 8x776f @16896..41728 | distK 8x128 u64 @41728..49920
  __shared__ __align__(16) char SM[49920];
  unsigned short* idxL = (unsigned short*)SM;
  unsigned* cnt  = (unsigned*)(SM + 16384);
  float*    thrS = (float*)(SM + 16640);

  // XCD-aware swizzle: batch pinned to an XCD pair
  int b = (blockIdx.x & 7) >> 1;
  int chunkI = ((blockIdx.x >> 3) << 1) | (blockIdx.x & 1);
  int q0 = chunkI << 6;
  int tid = threadIdx.x, w = tid >> 6, lane = tid & 63;
  int nl = lane & 15, quad = lane >> 4;

  if (tid < 64) cnt[tid] = 0u;

  const unsigned short* cb = xtb + (size_t)b*8192*96;
  const float* x2b = x2 + b*8192;

  // A-frags for ALL 4 query groups (phase 2) — every wave
  s16x8 af[4][3];
  #pragma unroll
  for (int g = 0; g < 4; ++g){
    const unsigned short* arow = xtb + (size_t)(b*8192 + q0 + 16*g + nl)*96 + quad*8;
    af[g][0] = *(const s16x8*)(arow);
    af[g][1] = *(const s16x8*)(arow + 32);
    af[g][2] = *(const s16x8*)(arow + 64);
  }
  float x2qA[4][4];
  #pragma unroll
  for (int g = 0; g < 4; ++g)
    #pragma unroll
    for (int r = 0; r < 4; ++r)
      x2qA[g][r] = x2[b*8192 + q0 + 16*g + quad*4 + r];

  // ---- phase 1: waves 0-3 threshold their group (bisection, identical arithmetic) ----
  if (w < 4){
    const unsigned short* arow = xtb + (size_t)(b*8192 + q0 + 16*w + nl)*96 + quad*8;
    s16x8 aw0 = *(const s16x8*)(arow);
    s16x8 aw1 = *(const s16x8*)(arow + 32);
    s16x8 aw2 = *(const s16x8*)(arow + 64);
    float x2qw[4];
    #pragma unroll
    for (int r = 0; r < 4; ++r) x2qw[r] = x2[b*8192 + q0 + 16*w + quad*4 + r];
    int stroke = q0 >> 8;
    f32x4 us[16];
    #pragma unroll
    for (int ss = 0; ss < 16; ++ss){
      int c0 = stroke*256 + ss*16;
      const unsigned short* brow = cb + (size_t)(c0 + nl)*96 + quad*8;
      s16x8 b0 = *(const s16x8*)(brow);
      s16x8 b1 = *(const s16x8*)(brow + 32);
      s16x8 b2 = *(const s16x8*)(brow + 64);
      us[ss] = score16v(aw0, aw1, aw2, b0, b1, b2, x2b[c0 + nl], x2qw);
    }
    float lo0=-4096.f, lo1=-4096.f, lo2=-4096.f, lo3=-4096.f;
    float hi0=257.f,   hi1=257.f,   hi2=257.f,   hi3=257.f;
    for (int it = 0; it < 13; ++it){
      float t0 = 0.5f*(lo0+hi0), t1 = 0.5f*(lo1+hi1), t2 = 0.5f*(lo2+hi2), t3 = 0.5f*(lo3+hi3);
      int c0=0, c1=0, c2=0, c3=0;
      #pragma unroll
      for (int ss = 0; ss < 16; ++ss){
        c0 += (us[ss][0] >= t0);
        c1 += (us[ss][1] >= t1);
        c2 += (us[ss][2] >= t2);
        c3 += (us[ss][3] >= t3);
      }
      unsigned p01 = (unsigned)c0 | ((unsigned)c1 << 16);
      unsigned p23 = (unsigned)c2 | ((unsigned)c3 << 16);
      #pragma unroll
      for (int off = 1; off <= 8; off <<= 1){
        p01 += (unsigned)__shfl_xor((int)p01, off);
        p23 += (unsigned)__shfl_xor((int)p23, off);
      }
      c0 = (int)(p01 & 0xFFFFu); c1 = (int)(p01 >> 16);
      c2 = (int)(p23 & 0xFFFFu); c3 = (int)(p23 >> 16);
      if (c0 >= 64) lo0 = t0; else hi0 = t0;
      if (c1 >= 64) lo1 = t1; else hi1 = t1;
      if (c2 >= 64) lo2 = t2; else hi2 = t2;
      if (c3 >= 64) lo3 = t3; else hi3 = t3;
    }
    if (nl == 0){
      thrS[16*w + quad*4 + 0] = lo0;
      thrS[16*w + quad*4 + 1] = lo1;
      thrS[16*w + quad*4 + 2] = lo2;
      thrS[16*w + quad*4 + 3] = lo3;
    }
  }
  __syncthreads();
  float thrA[4][4];
  #pragma unroll
  for (int g = 0; g < 4; ++g)
    #pragma unroll
    for (int r = 0; r < 4; ++r)
      thrA[g][r] = thrS[16*g + quad*4 + r];

  // ---- phase 2: wave w scans its 1024-cand range for ALL 64 queries (prefetched) ----
  {
    int s0w = w*64;
    s16x8 nb0, nb1, nb2; float nx2;
    {
      const unsigned short* brow = cb + (size_t)(s0w*16 + nl)*96 + quad*8;
      nb0 = *(const s16x8*)(brow);
      nb1 = *(const s16x8*)(brow + 32);
      nb2 = *(const s16x8*)(brow + 64);
      nx2 = x2b[s0w*16 + nl];
    }
    for (int si = 0; si < 64; ++si){
      s16x8 b0 = nb0, b1 = nb1, b2 = nb2;
      float x2c = nx2;
      int s = s0w + si;
      int sp = (si < 63) ? s + 1 : s;
      {
        const unsigned short* brow = cb + (size_t)(sp*16 + nl)*96 + quad*8;
        nb0 = *(const s16x8*)(brow);
        nb1 = *(const s16x8*)(brow + 32);
        nb2 = *(const s16x8*)(brow + 64);
        nx2 = x2b[sp*16 + nl];
      }
      int cand = s*16 + nl;
      #pragma unroll
      for (int g = 0; g < 4; ++g){
        f32x4 u = score16v(af[g][0], af[g][1], af[g][2], b0, b1, b2, x2c, x2qA[g]);
        #pragma unroll
        for (int r = 0; r < 4; ++r){
          if (u[r] >= thrA[g][r]){
            int ql = 16*g + quad*4 + r;
            unsigned pos = atomicAdd(&cnt[ql], 1u);
            if (pos < 128u) idxL[ql*128 + pos] = (unsigned short)cand;
          }
        }
      }
    }
  }
  __syncthreads();

  // ---- phase 3: exact fp32 distances + rank-based top-50 (wave-private, 8 q/wave) ----
  {
    float* rr = (float*)(SM + 16896) + w*776;       // [8 rows][97]
    unsigned long long* distK = (unsigned long long*)(SM + 41728) + w*128;
    int part = lane & 7, candl = lane >> 3;
    for (int rep = 0; rep < 8; ++rep){
      int q = 8*w + rep;
      int gq = b*8192 + q0 + q;
      unsigned craw = cnt[q];
      int cq = (int)(craw < 128u ? craw : 128u);
      float4 xq4[3];
      { const float4* xqp = (const float4*)(xt + (size_t)gq*96 + part*12);
        xq4[0] = xqp[0]; xq4[1] = xqp[1]; xq4[2] = xqp[2]; }
      int nch = (cq + 7) >> 3;
      float4 pv[3];
      auto loadChunk = [&](int ch, float4* dst){
        #pragma unroll
        for (int i = 0; i < 3; ++i){
          int f = i*64 + lane;
          int r_ = f / 24, c4 = f - r_*24;
          int k = ch*8 + r_;
          int kk = k < cq ? k : 0;
          int j = idxL[q*128 + kk];
          dst[i] = *(const float4*)(xt + (size_t)(b*8192 + j)*96 + c4*4);
        }
      };
      if (nch > 0) loadChunk(0, pv);
      for (int ch = 0; ch < nch; ++ch){
        float4 cv0 = pv[0], cv1 = pv[1], cv2 = pv[2];
        if (ch + 1 < nch) loadChunk(ch + 1, pv);
        {
          float4 cvs[3] = {cv0, cv1, cv2};
          #pragma unroll
          for (int i = 0; i < 3; ++i){
            int f = i*64 + lane;
            int r_ = f / 24, c4 = f - r_*24;
            float* dst = rr + r_*97 + c4*4;
            dst[0] = cvs[i].x; dst[1] = cvs[i].y; dst[2] = cvs[i].z; dst[3] = cvs[i].w;
          }
        }
        float acc = 0.f;
        const float* rrr = rr + candl*97 + part*12;
        #pragma unroll
        for (int i = 0; i < 3; ++i){
          float4 xv = xq4[i];
          float d0 = rrr[i*4+0] - xv.x, d1 = rrr[i*4+1] - xv.y;
          float d2 = rrr[i*4+2] - xv.z, d3 = rrr[i*4+3] - xv.w;
          acc += d0*d0 + d1*d1 + d2*d2 + d3*d3;
        }
        acc += __shfl_xor(acc, 1);
        acc += __shfl_xor(acc, 2);
        acc += __shfl_xor(acc, 4);
        if (part == 0){
          int kk = ch*8 + candl;
          unsigned cidx = (unsigned)idxL[q*128 + kk];   // stale for kk>=cq (unused)
          distK[kk] = (((unsigned long long)__float_as_uint(acc)) << 13) | cidx;
        }
      }
      // rank-based selection: key order == (d, idx) lexicographic order
      unsigned long long k0 = 0ull, k1 = 0ull;
      bool h0 = lane < cq, h1 = 64 + lane < cq;
      if (h0) k0 = distK[lane];
      if (h1) k1 = distK[64 + lane];
      unsigned r0 = 0, r1 = 0;
      #pragma unroll 4
      for (int j = 0; j < cq; ++j){
        unsigned long long kj = distK[j];
        r0 += (kj < k0);
        r1 += (kj < k1);
      }
      int* orow = i50 + (size_t)gq*50;
      if (h0 && r0 < 50u) orow[r0] = (int)(k0 & 8191ull);
      if (h1 && r1 < 50u) orow[r1] = (int)(k1 & 8191ull);
    }
  }
}

// ---------------- EdgeConv factorization via MFMA (hi/lo split) ----------------
__global__ __launch_bounds__(256) void k_g1p1(const float* __restrict__ xt,
                                              const unsigned short* __restrict__ w1h,
                                              const unsigned short* __restrict__ w1l,
                                              const float* __restrict__ bb1,
                                              float* __restrict__ g1,
                                              float* __restrict__ p1){
  int tid = threadIdx.x, w = tid >> 6, lane = tid & 63;
  int nl = lane & 15, quad = lane >> 4;
  int p0 = blockIdx.x*64;
  s16x8 ah[3], al[3];
  {
    const float* arow = xt + (size_t)(p0 + 16*w + nl)*96;
    #pragma unroll
    for (int kc = 0; kc < 3; ++kc){
      float4 v0 = *(const float4*)(arow + kc*32 + quad*8);
      float4 v1 = *(const float4*)(arow + kc*32 + quad*8 + 4);
      float tv[8] = {v0.x, v0.y, v0.z, v0.w, v1.x, v1.y, v1.z, v1.w};
      #pragma unroll
      for (int i = 0; i < 8; ++i){
        unsigned bits = __float_as_uint(tv[i]);
        ah[kc][i] = (short)(bits >> 16);
        float hv = __uint_as_float(bits & 0xFFFF0000u);
        al[kc][i] = (short)rne_bf16(tv[i] - hv);
      }
    }
  }
  #pragma unroll
  for (int nt = 0; nt < 7; ++nt){
    f32x4 Ca = {0.f,0.f,0.f,0.f}, Cc = {0.f,0.f,0.f,0.f};
    #pragma unroll
    for (int kc = 0; kc < 3; ++kc){
      size_t oa = (size_t)(nt*16 + nl)*96 + kc*32 + quad*8;
      size_t oc = (size_t)(nt*16 + 112 + nl)*96 + kc*32 + quad*8;
      s16x8 bha = *(const s16x8*)(w1h + oa);
      s16x8 bla = *(const s16x8*)(w1l + oa);
      s16x8 bhc = *(const s16x8*)(w1h + oc);
      s16x8 blc = *(const s16x8*)(w1l + oc);
      Ca = __builtin_amdgcn_mfma_f32_16x16x32_bf16(ah[kc], bha, Ca, 0, 0, 0);
      Ca = __builtin_amdgcn_mfma_f32_16x16x32_bf16(al[kc], bha, Ca, 0, 0, 0);
      Ca = __builtin_amdgcn_mfma_f32_16x16x32_bf16(ah[kc], bla, Ca, 0, 0, 0);
      Cc = __builtin_amdgcn_mfma_f32_16x16x32_bf16(ah[kc], bhc, Cc, 0, 0, 0);
      Cc = __builtin_amdgcn_mfma_f32_16x16x32_bf16(al[kc], bhc, Cc, 0, 0, 0);
      Cc = __builtin_amdgcn_mfma_f32_16x16x32_bf16(ah[kc], blc, Cc, 0, 0, 0);
    }
    int n = nt*16 + nl;
    float bias = (n < 110) ? bb1[n] : 0.f;
    #pragma unroll
    for (int r = 0; r < 4; ++r){
      int pt = p0 + 16*w + quad*4 + r;
      g1[(size_t)pt*112 + n] = Ca[r];
      p1[(size_t)pt*112 + n] = Cc[r] - Ca[r] + bias;
    }
  }
}

// ---------------- dense EdgeConv: MFMA (hi/lo split) + max over 50 ----------------
__global__ __launch_bounds__(512) void k_econv(const float* __restrict__ g1,
                                               const float* __restrict__ p1,
                                               const int* __restrict__ i50,
                                               const unsigned short* __restrict__ w2h,
                                               const unsigned short* __restrict__ w2l,
                                               const float* __restrict__ bb2,
                                               float* __restrict__ cin){
  __shared__ __align__(16) unsigned short BH[2*64*136];   // W2 hi | lo, row stride 136
  unsigned short* bhi = BH;
  unsigned short* blo = BH + 64*136;
  int tid = threadIdx.x, w = tid >> 6, lane = tid & 63;
  int nl = lane & 15, quad = lane >> 4;
  for (int idx = tid; idx < 8192; idx += 512){
    int row = idx >> 7, k = idx & 127;
    bhi[row*136 + k] = w2h[idx];
    blo[row*136 + k] = w2l[idx];
  }
  __syncthreads();

  // XCD-pair batch swizzle (g1/p1 L2 locality)
  int blk = blockIdx.x;
  int b = (blk & 7) >> 1;
  int qi = ((blk >> 3) << 1) | (blk & 1);       // 0..1023
  int gq = b*8192 + qi*8 + w;
  const int* jrow = i50 + (size_t)gq*50;
  const float* pr = p1 + (size_t)gq*112;
  float4 pf[8];
  #pragma unroll
  for (int ks = 0; ks < 4; ++ks){
    if (ks < 3 || quad < 2){
      pf[2*ks]   = *(const float4*)(pr + ks*32 + quad*8);
      pf[2*ks+1] = *(const float4*)(pr + ks*32 + quad*8 + 4);
    } else {
      pf[2*ks] = make_float4(0.f,0.f,0.f,0.f); pf[2*ks+1] = make_float4(0.f,0.f,0.f,0.f);
    }
  }
  float m4[4] = {-3.4e38f, -3.4e38f, -3.4e38f, -3.4e38f};

  for (int rt = 0; rt < 4; ++rt){
    int e = rt*16 + nl;
    int j = jrow[e < 50 ? e : 49];
    const float* gr = g1 + (size_t)(b*8192 + j)*112;
    s16x8 ah[4], al[4];
    #pragma unroll
    for (int ks = 0; ks < 4; ++ks){
      if (ks == 3 && quad >= 2){
        #pragma unroll
        for (int i = 0; i < 8; ++i){ ah[3][i] = 0; al[3][i] = 0; }
      } else {
        int off = ks*32 + quad*8;
        float4 g0  = *(const float4*)(gr + off);
        float4 g1v = *(const float4*)(gr + off + 4);
        float4 p0v = pf[2*ks], p1v = pf[2*ks+1];
        float tv[8] = { leaky(g0.x+p0v.x),  leaky(g0.y+p0v.y),  leaky(g0.z+p0v.z),  leaky(g0.w+p0v.w),
                        leaky(g1v.x+p1v.x), leaky(g1v.y+p1v.y), leaky(g1v.z+p1v.z), leaky(g1v.w+p1v.w) };
        #pragma unroll
        for (int i = 0; i < 8; ++i){
          unsigned bits = __float_as_uint(tv[i]);
          ah[ks][i] = (short)(bits >> 16);
          float hv = __uint_as_float(bits & 0xFFFF0000u);
          al[ks][i] = (short)rne_bf16(tv[i] - hv);
        }
      }
    }
    f32x4 C[4] = {{0.f,0.f,0.f,0.f},{0.f,0.f,0.f,0.f},{0.f,0.f,0.f,0.f},{0.f,0.f,0.f,0.f}};
    #pragma unroll
    for (int ks = 0; ks < 4; ++ks){
      int ko = ks*64 + quad*16;
      #pragma unroll
      for (int ct = 0; ct < 4; ++ct){
        const char* rp = (const char*)bhi + (ct*16 + nl)*272 + ko;
        s16x8 bh  = *(const s16x8*)(rp);
        s16x8 blv = *(const s16x8*)(rp + 64*136*2);
        C[ct] = __builtin_amdgcn_mfma_f32_16x16x32_bf16(ah[ks], bh,  C[ct], 0, 0, 0);
        C[ct] = __builtin_amdgcn_mfma_f32_16x16x32_bf16(al[ks], bh,  C[ct], 0, 0, 0);
        C[ct] = __builtin_amdgcn_mfma_f32_16x16x32_bf16(ah[ks], blv, C[ct], 0, 0, 0);
      }
    }
    if (rt < 3){
      #pragma unroll
      for (int ct = 0; ct < 4; ++ct)
        #pragma unroll
        for (int r = 0; r < 4; ++r) m4[ct] = fmaxf(m4[ct], C[ct][r]);
    } else {
      if (quad == 0){
        #pragma unroll
        for (int ct = 0; ct < 4; ++ct){
          m4[ct] = fmaxf(m4[ct], C[ct][0]);
          m4[ct] = fmaxf(m4[ct], C[ct][1]);
        }
      }
    }
  }
  #pragma unroll
  for (int ct = 0; ct < 4; ++ct){
    m4[ct] = fmaxf(m4[ct], __shfl_xor(m4[ct], 16));
    m4[ct] = fmaxf(m4[ct], __shfl_xor(m4[ct], 32));
  }
  if (quad == 0){
    #pragma unroll
    for (int ct = 0; ct < 4; ++ct){
      int o = ct*16 + nl;
      cin[(size_t)gq*64 + o] = leaky(m4[ct] + bb2[o]);
    }
  }
}

// ---------------- downsample conv (1,3) stride (1,2) pad (0,1) ----------------
__global__ __launch_bounds__(256) void k_down(const float* __restrict__ cin,
                                              const float* __restrict__ wdt,
                                              const float* __restrict__ bias,
                                              float* __restrict__ outp){
  int blk = blockIdx.x;
  int b = blk >> 8, r = blk & 255, s = r >> 3, oq = r & 7;
  int t = threadIdx.x;
  __shared__ __align__(16) float L[34*68];
  for (int k = t; k < 34*64; k += 256){
    int rr = k >> 6, i = k & 63;
    int pp = oq*32 - 1 + rr;
    float v = 0.f;
    if (pp >= 0 && pp < 256) v = cin[(size_t)(b*8192 + s*256 + pp)*64 + i];
    L[rr*68 + i] = v;
  }
  __syncthreads();
  #pragma unroll
  for (int kk = 0; kk < 4; ++kk){
    int ow = kk*256 + t;
    int o = ow >> 4, wl = ow & 15;
    float acc = bias[o];
    #pragma unroll
    for (int tt = 0; tt < 3; ++tt){
      int rr = 2*wl + tt;
      const float4* lv4 = (const float4*)(L + rr*68);
      const float4* wv4 = (const float4*)(wdt + tt*4096 + o*64);
      #pragma unroll
      for (int i4 = 0; i4 < 16; ++i4){
        float4 lv = lv4[i4], wv = wv4[i4];
        acc += wv.x*lv.x + wv.y*lv.y + wv.z*lv.z + wv.w*lv.w;
      }
    }
    int w_ = oq*16 + wl;
    outp[16384 + (size_t)((b*64 + o)*32 + s)*128 + w_] = leaky(acc);
  }
}

extern "C" void kernel_launch(void* const* d_in, const int* in_sizes, int n_in,
                              void* d_out, int out_size, void* d_ws, size_t ws_size,
                              hipStream_t stream){
  (void)in_sizes; (void)n_in; (void)out_size; (void)ws_size;
  const float* sparse = (const float*)d_in[0];
  const float* dense  = (const float*)d_in[1];
  const float* spW1   = (const float*)d_in[2];
  const float* spb1   = (const float*)d_in[3];
  const float* spW2   = (const float*)d_in[4];
  const float* spb2   = (const float*)d_in[5];
  const float* dnW1   = (const float*)d_in[6];
  const float* dnb1   = (const float*)d_in[7];
  const float* dnW2   = (const float*)d_in[8];
  const float* dnb2   = (const float*)d_in[9];
  const float* dsW    = (const float*)d_in[10];
  const float* dsb    = (const float*)d_in[11];
  float* out = (float*)d_out;

  float* w    = (float*)d_ws;                  // 63.5 MB
  float* xt   = w;                             // 3,145,728
  float* x2   = w + 3145728;                   //    32,768
  float* g1   = w + 3178496;                   // 3,670,016 (stride 112)
  float* p1   = w + 6848512;                   // 3,670,016
  int*   i50  = (int*)(w + 10518528);          // 1,638,400
  float* cin  = w + 12156928;                  // 2,097,152
  float* xtsp = w + 14254080;                  //    12,288
  unsigned short* xtb = (unsigned short*)(w + 14266368);  // 3,145,728 u16
  unsigned short* w1h = (unsigned short*)(w + 15839232);  // 21504 u16
  unsigned short* w1l = (unsigned short*)(w + 15849984);
  unsigned short* w2h = (unsigned short*)(w + 15860736);  // 8192 u16
  unsigned short* w2l = (unsigned short*)(w + 15864832);
  float* wdt  = w + 15868928;                  // 12,288

  k_prep        <<<164,  256, 0, stream>>>(dnW1, dnW2, dsW, w1h, w1l, w2h, w2l, wdt);
  k_build_xt    <<<512,  256, 0, stream>>>(dense, sparse, xt, xtb, x2);
  k_sparse_union<<<128,  256, 0, stream>>>(sparse, dense, xtsp);
  k_sparse_gcn  <<<128,  192, 0, stream>>>(xtsp, spW1, spb1, spW2, spb2, out);
  k_knn         <<<512,  512, 0, stream>>>(xtb, x2, xt, i50);
  k_g1p1        <<<512,  256, 0, stream>>>(xt, w1h, w1l, dnb1, g1, p1);
  k_econv       <<<4096, 512, 0, stream>>>(g1, p1, i50, w2h, w2l, dnb2, cin);
  k_down        <<<1024, 256, 0, stream>>>(cin, wdt, dsb, out);
}

// Round 10
// 575.455 us; speedup vs baseline: 1.1334x; 1.1334x over previous
//
#include <hip/hip_runtime.h>

// SDGraphUNet on MI355X — round 9: fusion + co-scheduling.
//  k_stage1 : build_xt(512 blks) + prep(164) + sparse_union(128)  [grid 804]
//  k_stage2 : knn R7-config(512 blks, FIRST) + g1p1(512) + sparse_gcn(128)
//             g1p1/gcn fill the CUs and pipes knn leaves idle.   [grid 1152]
//  k_econv  : + depth-1 g-row prefetch.
//  k_down   : unchanged.
//  All arithmetic identical to R7/R8 => absmax unchanged.
//
// ws unchanged: 63.5 MB

#define LEAKK 0.2f

typedef short s16x8 __attribute__((ext_vector_type(8)));
typedef float f32x4 __attribute__((ext_vector_type(4)));

__device__ __forceinline__ float leaky(float x){ return x > 0.f ? x : LEAKK*x; }
__device__ __forceinline__ unsigned rne_bf16(float v){
  unsigned bits = __float_as_uint(v);
  return (bits + 0x7FFFu + ((bits >> 16) & 1u)) >> 16;
}

// ---- 16 queries x 16 cands -> u = 256 - d_approx; shared by both kNN phases ----
__device__ __forceinline__ f32x4 score16v(s16x8 a0, s16x8 a1, s16x8 a2,
                                          s16x8 b0, s16x8 b1, s16x8 b2,
                                          float x2c, const float* x2q){
  f32x4 acc = {0.f,0.f,0.f,0.f};
  acc = __builtin_amdgcn_mfma_f32_16x16x32_bf16(a0, b0, acc, 0, 0, 0);
  acc = __builtin_amdgcn_mfma_f32_16x16x32_bf16(a1, b1, acc, 0, 0, 0);
  acc = __builtin_amdgcn_mfma_f32_16x16x32_bf16(a2, b2, acc, 0, 0, 0);
  f32x4 u;
  #pragma unroll
  for (int r = 0; r < 4; ++r)
    u[r] = (__builtin_fmaf(2.f, acc[r], -x2c) - x2q[r]) + 256.f;
  return u;
}

// =============== stage 1: build_xt + prep + sparse_union ===============
__global__ __launch_bounds__(256) void k_stage1(const float* __restrict__ dense,
                                                const float* __restrict__ sparse,
                                                const float* __restrict__ W1,
                                                const float* __restrict__ W2,
                                                const float* __restrict__ Wd,
                                                float* __restrict__ xt,
                                                unsigned short* __restrict__ xtb,
                                                float* __restrict__ x2,
                                                float* __restrict__ xtsp,
                                                unsigned short* __restrict__ w1h,
                                                unsigned short* __restrict__ w1l,
                                                unsigned short* __restrict__ w2h,
                                                unsigned short* __restrict__ w2l,
                                                float* __restrict__ wdt){
  int blk = blockIdx.x, tid = threadIdx.x;
  if (blk < 512){
    // ---- build dense union features (fp32 + bf16) + x2 ----
    __shared__ float D[32*65];
    __shared__ float sArr[64];
    int q4 = blk & 3, bs = blk >> 2, b = bs >> 5, s = bs & 31;
    if (tid < 64) sArr[tid] = sparse[(b*64 + tid)*32 + s];
    for (int i = tid; i < 2048; i += 256){
      int c = i >> 6, pp = i & 63;
      D[c*65 + pp] = dense[(((b*32 + c)*32 + s) << 8) + q4*64 + pp];
    }
    __syncthreads();
    float ss = 0.f;
    #pragma unroll
    for (int ch = 0; ch < 64; ++ch){ float v = sArr[ch]; ss = __builtin_fmaf(v, v, ss); }
    size_t base = ((size_t)b*8192 + s*256 + q4*64)*96;
    for (int i = tid; i < 6144; i += 256){
      int pp = i / 96, c = i - pp*96;
      float v = (c < 32) ? D[c*65 + pp] : sArr[c - 32];
      xt[base + i] = v;
      xtb[base + i] = (unsigned short)rne_bf16(v);
    }
    if (tid < 64){
      float a = ss;
      #pragma unroll
      for (int c = 0; c < 32; ++c){ float v = D[c*65 + tid]; a = __builtin_fmaf(v, v, a); }
      x2[b*8192 + s*256 + q4*64 + tid] = a;
    }
  } else if (blk < 676){
    // ---- prep: hi/lo splits + Wd transpose ----
    int idx = (blk - 512)*256 + tid;            // < 41984
    if (idx < 21504){
      int row = idx / 96, k = idx - row*96;
      float v = 0.f;
      if (row < 110) v = W1[row*192 + k];
      else if (row >= 112 && row < 222) v = W1[(row - 112)*192 + 96 + k];
      unsigned bits = __float_as_uint(v);
      w1h[idx] = (unsigned short)(bits >> 16);
      float hv = __uint_as_float(bits & 0xFFFF0000u);
      w1l[idx] = (unsigned short)rne_bf16(v - hv);
    } else if (idx < 29696){
      int j = idx - 21504;
      int row = j >> 7, k = j & 127;
      float v = (k < 110) ? W2[row*110 + k] : 0.f;
      unsigned bits = __float_as_uint(v);
      w2h[j] = (unsigned short)(bits >> 16);
      float hv = __uint_as_float(bits & 0xFFFF0000u);
      w2l[j] = (unsigned short)rne_bf16(v - hv);
    } else if (idx < 41984){
      int j = idx - 29696;                      // tt*4096 + o*64 + i
      int tt = j >> 12, rest = j & 4095, o = rest >> 6, i = rest & 63;
      wdt[j] = Wd[(o*64 + i)*3 + tt];
    }
  } else {
    // ---- sparse union (max over points + concat) ----
    int r = blk - 676;
    int b = r >> 5, i = r & 31;
    int w = tid >> 6, l = tid & 63;
    if (w == 0) xtsp[(b*32 + i)*96 + l] = sparse[(b*64 + l)*32 + i];
    for (int c = w; c < 32; c += 4){
      const float* row = dense + (((size_t)(b*32 + c)*32 + i) << 8);
      float v = fmaxf(fmaxf(row[l], row[l+64]), fmaxf(row[l+128], row[l+192]));
      for (int off = 32; off > 0; off >>= 1) v = fmaxf(v, __shfl_down(v, off));
      if (l == 0) xtsp[(b*32 + i)*96 + 64 + c] = v;
    }
  }
}

// =============== stage 2: knn (blocks 0-511) + g1p1 (512-1023) + sparse_gcn ===============
__global__ __launch_bounds__(256) void k_stage2(const unsigned short* __restrict__ xtb,
                                                const float* __restrict__ x2,
                                                const float* __restrict__ xt,
                                                int* __restrict__ i50,
                                                const unsigned short* __restrict__ w1h,
                                                const unsigned short* __restrict__ w1l,
                                                const float* __restrict__ dnb1,
                                                float* __restrict__ g1,
                                                float* __restrict__ p1,
                                                const float* __restrict__ xtsp,
                                                const float* __restrict__ spW1,
                                                const float* __restrict__ spb1,
                                                const float* __restrict__ spW2,
                                                const float* __restrict__ spb2,
                                                float* __restrict__ outp){
  __shared__ __align__(16) char SM[33408];
  int blk = blockIdx.x, tid = threadIdx.x;

  if (blk < 512){
    // ================= fused kNN (R7 config: 4 waves, cap 128) =================
    unsigned short* idxL = (unsigned short*)SM;
    unsigned* cnt  = (unsigned*)(SM + 16384);
    float*    thrS = (float*)(SM + 16640);
    int b = (blk & 7) >> 1;
    int chunkI = ((blk >> 3) << 1) | (blk & 1);
    int q0 = chunkI << 6;
    int w = tid >> 6, lane = tid & 63;
    int nl = lane & 15, quad = lane >> 4;
    if (tid < 64) cnt[tid] = 0u;
    const unsigned short* cb = xtb + (size_t)b*8192*96;
    const float* x2b = x2 + b*8192;

    s16x8 af[4][3];
    #pragma unroll
    for (int g = 0; g < 4; ++g){
      const unsigned short* arow = xtb + (size_t)(b*8192 + q0 + 16*g + nl)*96 + quad*8;
      af[g][0] = *(const s16x8*)(arow);
      af[g][1] = *(const s16x8*)(arow + 32);
      af[g][2] = *(const s16x8*)(arow + 64);
    }
    float x2qA[4][4];
    #pragma unroll
    for (int g = 0; g < 4; ++g)
      #pragma unroll
      for (int r = 0; r < 4; ++r)
        x2qA[g][r] = x2[b*8192 + q0 + 16*g + quad*4 + r];

    // phase 1: wave w thresholds its group (bisection on mate scores)
    {
      const unsigned short* arow = xtb + (size_t)(b*8192 + q0 + 16*w + nl)*96 + quad*8;
      s16x8 aw0 = *(const s16x8*)(arow);
      s16x8 aw1 = *(const s16x8*)(arow + 32);
      s16x8 aw2 = *(const s16x8*)(arow + 64);
      float x2qw[4];
      #pragma unroll
      for (int r = 0; r < 4; ++r) x2qw[r] = x2[b*8192 + q0 + 16*w + quad*4 + r];
      int stroke = q0 >> 8;
      f32x4 us[16];
      #pragma unroll
      for (int ss = 0; ss < 16; ++ss){
        int c0 = stroke*256 + ss*16;
        const unsigned short* brow = cb + (size_t)(c0 + nl)*96 + quad*8;
        s16x8 b0 = *(const s16x8*)(brow);
        s16x8 b1 = *(const s16x8*)(brow + 32);
        s16x8 b2 = *(const s16x8*)(brow + 64);
        us[ss] = score16v(aw0, aw1, aw2, b0, b1, b2, x2b[c0 + nl], x2qw);
      }
      float lo0=-4096.f, lo1=-4096.f, lo2=-4096.f, lo3=-4096.f;
      float hi0=257.f,   hi1=257.f,   hi2=257.f,   hi3=257.f;
      for (int it = 0; it < 13; ++it){
        float t0 = 0.5f*(lo0+hi0), t1 = 0.5f*(lo1+hi1), t2 = 0.5f*(lo2+hi2), t3 = 0.5f*(lo3+hi3);
        int c0=0, c1=0, c2=0, c3=0;
        #pragma unroll
        for (int ss = 0; ss < 16; ++ss){
          c0 += (us[ss][0] >= t0);
          c1 += (us[ss][1] >= t1);
          c2 += (us[ss][2] >= t2);
          c3 += (us[ss][3] >= t3);
        }
        unsigned p01 = (unsigned)c0 | ((unsigned)c1 << 16);
        unsigned p23 = (unsigned)c2 | ((unsigned)c3 << 16);
        #pragma unroll
        for (int off = 1; off <= 8; off <<= 1){
          p01 += (unsigned)__shfl_xor((int)p01, off);
          p23 += (unsigned)__shfl_xor((int)p23, off);
        }
        c0 = (int)(p01 & 0xFFFFu); c1 = (int)(p01 >> 16);
        c2 = (int)(p23 & 0xFFFFu); c3 = (int)(p23 >> 16);
        if (c0 >= 64) lo0 = t0; else hi0 = t0;
        if (c1 >= 64) lo1 = t1; else hi1 = t1;
        if (c2 >= 64) lo2 = t2; else hi2 = t2;
        if (c3 >= 64) lo3 = t3; else hi3 = t3;
      }
      if (nl == 0){
        thrS[16*w + quad*4 + 0] = lo0;
        thrS[16*w + quad*4 + 1] = lo1;
        thrS[16*w + quad*4 + 2] = lo2;
        thrS[16*w + quad*4 + 3] = lo3;
      }
    }
    __syncthreads();
    float thrA[4][4];
    #pragma unroll
    for (int g = 0; g < 4; ++g)
      #pragma unroll
      for (int r = 0; r < 4; ++r)
        thrA[g][r] = thrS[16*g + quad*4 + r];

    // phase 2: wave w scans its 2048-cand range for all 64 queries (prefetched)
    {
      int s0w = w*128;
      s16x8 nb0, nb1, nb2; float nx2;
      {
        const unsigned short* brow = cb + (size_t)(s0w*16 + nl)*96 + quad*8;
        nb0 = *(const s16x8*)(brow);
        nb1 = *(const s16x8*)(brow + 32);
        nb2 = *(const s16x8*)(brow + 64);
        nx2 = x2b[s0w*16 + nl];
      }
      for (int si = 0; si < 128; ++si){
        s16x8 b0 = nb0, b1 = nb1, b2 = nb2;
        float x2c = nx2;
        int s = s0w + si;
        int sp = (si < 127) ? s + 1 : s;
        {
          const unsigned short* brow = cb + (size_t)(sp*16 + nl)*96 + quad*8;
          nb0 = *(const s16x8*)(brow);
          nb1 = *(const s16x8*)(brow + 32);
          nb2 = *(const s16x8*)(brow + 64);
          nx2 = x2b[sp*16 + nl];
        }
        int cand = s*16 + nl;
        #pragma unroll
        for (int g = 0; g < 4; ++g){
          f32x4 u = score16v(af[g][0], af[g][1], af[g][2], b0, b1, b2, x2c, x2qA[g]);
          #pragma unroll
          for (int r = 0; r < 4; ++r){
            if (u[r] >= thrA[g][r]){
              int ql = 16*g + quad*4 + r;
              unsigned pos = atomicAdd(&cnt[ql], 1u);
              if (pos < 128u) idxL[ql*128 + pos] = (unsigned short)cand;
            }
          }
        }
      }
    }
    __syncthreads();

    // phase 3: exact fp32 distances + rank-based top-50 (wave-private)
    {
      float* rr = (float*)(SM + 16896) + w*776;       // [8 rows][97]
      unsigned long long* distK = (unsigned long long*)(SM + 29312) + w*128;
      int part = lane & 7, candl = lane >> 3;
      for (int rep = 0; rep < 16; ++rep){
        int q = 16*w + rep;
        int gq = b*8192 + q0 + q;
        unsigned craw = cnt[q];
        int cq = (int)(craw < 128u ? craw : 128u);
        float4 xq4[3];
        { const float4* xqp = (const float4*)(xt + (size_t)gq*96 + part*12);
          xq4[0] = xqp[0]; xq4[1] = xqp[1]; xq4[2] = xqp[2]; }
        int nch = (cq + 7) >> 3;
        float4 pv[3];
        auto loadChunk = [&](int ch, float4* dst){
          #pragma unroll
          for (int i = 0; i < 3; ++i){
            int f = i*64 + lane;
            int r_ = f / 24, c4 = f - r_*24;
            int k = ch*8 + r_;
            int kk = k < cq ? k : 0;
            int j = idxL[q*128 + kk];
            dst[i] = *(const float4*)(xt + (size_t)(b*8192 + j)*96 + c4*4);
          }
        };
        if (nch > 0) loadChunk(0, pv);
        for (int ch = 0; ch < nch; ++ch){
          float4 cv0 = pv[0], cv1 = pv[1], cv2 = pv[2];
          if (ch + 1 < nch) loadChunk(ch + 1, pv);
          {
            float4 cvs[3] = {cv0, cv1, cv2};
            #pragma unroll
            for (int i = 0; i < 3; ++i){
              int f = i*64 + lane;
              int r_ = f / 24, c4 = f - r_*24;
              float* dst = rr + r_*97 + c4*4;
              dst[0] = cvs[i].x; dst[1] = cvs[i].y; dst[2] = cvs[i].z; dst[3] = cvs[i].w;
            }
          }
          float acc = 0.f;
          const float* rrr = rr + candl*97 + part*12;
          #pragma unroll
          for (int i = 0; i < 3; ++i){
            float4 xv = xq4[i];
            float d0 = rrr[i*4+0] - xv.x, d1 = rrr[i*4+1] - xv.y;
            float d2 = rrr[i*4+2] - xv.z, d3 = rrr[i*4+3] - xv.w;
            acc += d0*d0 + d1*d1 + d2*d2 + d3*d3;
          }
          acc += __shfl_xor(acc, 1);
          acc += __shfl_xor(acc, 2);
          acc += __shfl_xor(acc, 4);
          if (part == 0){
            int kk = ch*8 + candl;
            unsigned cidx = (unsigned)idxL[q*128 + kk];   // stale for kk>=cq (unused)
            distK[kk] = (((unsigned long long)__float_as_uint(acc)) << 13) | cidx;
          }
        }
        unsigned long long k0 = 0ull, k1 = 0ull;
        bool h0 = lane < cq, h1 = 64 + lane < cq;
        if (h0) k0 = distK[lane];
        if (h1) k1 = distK[64 + lane];
        unsigned r0 = 0, r1 = 0;
        #pragma unroll 4
        for (int j = 0; j < cq; ++j){
          unsigned long long kj = distK[j];
          r0 += (kj < k0);
          r1 += (kj < k1);
        }
        int* orow = i50 + (size_t)gq*50;
        if (h0 && r0 < 50u) orow[r0] = (int)(k0 & 8191ull);
        if (h1 && r1 < 50u) orow[r1] = (int)(k1 & 8191ull);
      }
    }
  } else if (blk < 1024){
    // ================= EdgeConv factorization via MFMA (hi/lo split) =================
    int w = tid >> 6, lane = tid & 63;
    int nl = lane & 15, quad = lane >> 4;
    int p0 = (blk - 512)*64;
    s16x8 ah[3], al[3];
    {
      const float* arow = xt + (size_t)(p0 + 16*w + nl)*96;
      #pragma unroll
      for (int kc = 0; kc < 3; ++kc){
        float4 v0 = *(const float4*)(arow + kc*32 + quad*8);
        float4 v1 = *(const float4*)(arow + kc*32 + quad*8 + 4);
        float tv[8] = {v0.x, v0.y, v0.z, v0.w, v1.x, v1.y, v1.z, v1.w};
        #pragma unroll
        for (int i = 0; i < 8; ++i){
          unsigned bits = __float_as_uint(tv[i]);
          ah[kc][i] = (short)(bits >> 16);
          float hv = __uint_as_float(bits & 0xFFFF0000u);
          al[kc][i] = (short)rne_bf16(tv[i] - hv);
        }
      }
    }
    #pragma unroll
    for (int nt = 0; nt < 7; ++nt){
      f32x4 Ca = {0.f,0.f,0.f,0.f}, Cc = {0.f,0.f,0.f,0.f};
      #pragma unroll
      for (int kc = 0; kc < 3; ++kc){
        size_t oa = (size_t)(nt*16 + nl)*96 + kc*32 + quad*8;
        size_t oc = (size_t)(nt*16 + 112 + nl)*96 + kc*32 + quad*8;
        s16x8 bha = *(const s16x8*)(w1h + oa);
        s16x8 bla = *(const s16x8*)(w1l + oa);
        s16x8 bhc = *(const s16x8*)(w1h + oc);
        s16x8 blc = *(const s16x8*)(w1l + oc);
        Ca = __builtin_amdgcn_mfma_f32_16x16x32_bf16(ah[kc], bha, Ca, 0, 0, 0);
        Ca = __builtin_amdgcn_mfma_f32_16x16x32_bf16(al[kc], bha, Ca, 0, 0, 0);
        Ca = __builtin_amdgcn_mfma_f32_16x16x32_bf16(ah[kc], bla, Ca, 0, 0, 0);
        Cc = __builtin_amdgcn_mfma_f32_16x16x32_bf16(ah[kc], bhc, Cc, 0, 0, 0);
        Cc = __builtin_amdgcn_mfma_f32_16x16x32_bf16(al[kc], bhc, Cc, 0, 0, 0);
        Cc = __builtin_amdgcn_mfma_f32_16x16x32_bf16(ah[kc], blc, Cc, 0, 0, 0);
      }
      int n = nt*16 + nl;
      float bias = (n < 110) ? dnb1[n] : 0.f;
      #pragma unroll
      for (int r = 0; r < 4; ++r){
        int pt = p0 + 16*w + quad*4 + r;
        g1[(size_t)pt*112 + n] = Ca[r];
        p1[(size_t)pt*112 + n] = Cc[r] - Ca[r] + bias;
      }
    }
  } else {
    // ================= sparse GCN (k=2 over 32 strokes) =================
    float* X   = (float*)SM;              // 3072 f
    float* x2l = (float*)(SM + 12288);    // 32 f
    float* dd  = (float*)(SM + 12416);    // 32 f
    int*   nbb = (int*)(SM + 12544);      // 2 i
    float* E   = (float*)(SM + 12560);    // 192 f
    float* H1  = (float*)(SM + 13328);    // 156 f
    int r = blk - 1024;
    int b = r >> 5, i = r & 31, t = tid;
    for (int k = t; k < 3072; k += 256) X[k] = xtsp[b*3072 + k];
    __syncthreads();
    if (t < 32){
      float s = 0.f;
      for (int c = 0; c < 96; ++c){ float v = X[t*96+c]; s += v*v; }
      x2l[t] = s;
    }
    __syncthreads();
    if (t < 32){
      float dot = 0.f;
      for (int c = 0; c < 96; ++c) dot += X[i*96+c]*X[t*96+c];
      dd[t] = x2l[i] - 2.f*dot + x2l[t];
    }
    __syncthreads();
    if (t == 0){
      int s0 = -1, s1 = -1;
      for (int j = 0; j < 32; ++j){
        float dj = dd[j];
        if (s0 < 0 || dj < dd[s0]){ s1 = s0; s0 = j; }
        else if (s1 < 0 || dj < dd[s1]){ s1 = j; }
      }
      nbb[0] = s0; nbb[1] = s1;
    }
    __syncthreads();
    float acc = -3.4e38f;
    for (int n = 0; n < 2; ++n){
      int j = nbb[n];
      if (t < 96){ E[t] = X[j*96+t] - X[i*96+t]; E[96+t] = X[i*96+t]; }
      __syncthreads();
      if (t < 156){
        float h = spb1[t];
        const float* wr = spW1 + t*192;
        for (int k = 0; k < 192; ++k) h += E[k]*wr[k];
        H1[t] = leaky(h);
      }
      __syncthreads();
      if (t < 128){
        float h = spb2[t];
        const float* wr = spW2 + t*156;
        for (int m = 0; m < 156; ++m) h += H1[m]*wr[m];
        acc = fmaxf(acc, leaky(h));
      }
      __syncthreads();
    }
    if (t < 128) outp[(b*128 + t)*32 + i] = acc;
  }
}

// ---------------- dense EdgeConv: MFMA (hi/lo split) + max over 50, g-prefetch ----------------
__global__ __launch_bounds__(512) void k_econv(const float* __restrict__ g1,
                                               const float* __restrict__ p1,
                                               const int* __restrict__ i50,
                                               const unsigned short* __restrict__ w2h,
                                               const unsigned short* __restrict__ w2l,
                                               const float* __restrict__ bb2,
                                               float* __restrict__ cin){
  __shared__ __align__(16) unsigned short BH[2*64*136];   // W2 hi | lo, row stride 136
  unsigned short* bhi = BH;
  int tid = threadIdx.x, w = tid >> 6, lane = tid & 63;
  int nl = lane & 15, quad = lane >> 4;
  for (int idx = tid; idx < 8192; idx += 512){
    int row = idx >> 7, k = idx & 127;
    bhi[row*136 + k] = w2h[idx];
    BH[64*136 + row*136 + k] = w2l[idx];
  }
  __syncthreads();

  // XCD-pair batch swizzle (g1/p1 L2 locality)
  int blk = blockIdx.x;
  int b = (blk & 7) >> 1;
  int qi = ((blk >> 3) << 1) | (blk & 1);       // 0..1023
  int gq = b*8192 + qi*8 + w;
  const int* jrow = i50 + (size_t)gq*50;
  const float* pr = p1 + (size_t)gq*112;
  float4 pf[8];
  #pragma unroll
  for (int ks = 0; ks < 4; ++ks){
    if (ks < 3 || quad < 2){
      pf[2*ks]   = *(const float4*)(pr + ks*32 + quad*8);
      pf[2*ks+1] = *(const float4*)(pr + ks*32 + quad*8 + 4);
    } else {
      pf[2*ks] = make_float4(0.f,0.f,0.f,0.f); pf[2*ks+1] = make_float4(0.f,0.f,0.f,0.f);
    }
  }
  float m4[4] = {-3.4e38f, -3.4e38f, -3.4e38f, -3.4e38f};

  float4 gb[8];
  auto loadG = [&](int e){
    int ecl = e < 50 ? e : 49;
    int j = jrow[ecl];
    const float* gr = g1 + (size_t)(b*8192 + j)*112;
    #pragma unroll
    for (int ks = 0; ks < 4; ++ks){
      if (ks == 3 && quad >= 2){
        gb[2*ks] = make_float4(0.f,0.f,0.f,0.f); gb[2*ks+1] = make_float4(0.f,0.f,0.f,0.f);
      } else {
        int off = ks*32 + quad*8;
        gb[2*ks]   = *(const float4*)(gr + off);
        gb[2*ks+1] = *(const float4*)(gr + off + 4);
      }
    }
  };
  loadG(nl);

  for (int rt = 0; rt < 4; ++rt){
    s16x8 ah[4], al[4];
    #pragma unroll
    for (int ks = 0; ks < 4; ++ks){
      float4 g0  = gb[2*ks];
      float4 g1v = gb[2*ks+1];
      float4 p0v = pf[2*ks], p1v = pf[2*ks+1];
      float tv[8] = { leaky(g0.x+p0v.x),  leaky(g0.y+p0v.y),  leaky(g0.z+p0v.z),  leaky(g0.w+p0v.w),
                      leaky(g1v.x+p1v.x), leaky(g1v.y+p1v.y), leaky(g1v.z+p1v.z), leaky(g1v.w+p1v.w) };
      #pragma unroll
      for (int i = 0; i < 8; ++i){
        unsigned bits = __float_as_uint(tv[i]);
        ah[ks][i] = (short)(bits >> 16);
        float hv = __uint_as_float(bits & 0xFFFF0000u);
        al[ks][i] = (short)rne_bf16(tv[i] - hv);
      }
    }
    if (rt < 3) loadG((rt+1)*16 + nl);         // prefetch next edge rows
    f32x4 C[4] = {{0.f,0.f,0.f,0.f},{0.f,0.f,0.f,0.f},{0.f,0.f,0.f,0.f},{0.f,0.f,0.f,0.f}};
    #pragma unroll
    for (int ks = 0; ks < 4; ++ks){
      int ko = ks*64 + quad*16;
      #pragma unroll
      for (int ct = 0; ct < 4; ++ct){
        const char* rp = (const char*)bhi + (ct*16 + nl)*272 + ko;
        s16x8 bh  = *(const s16x8*)(rp);
        s16x8 blv = *(const s16x8*)(rp + 64*136*2);
        C[ct] = __builtin_amdgcn_mfma_f32_16x16x32_bf16(ah[ks], bh,  C[ct], 0, 0, 0);
        C[ct] = __builtin_amdgcn_mfma_f32_16x16x32_bf16(al[ks], bh,  C[ct], 0, 0, 0);
        C[ct] = __builtin_amdgcn_mfma_f32_16x16x32_bf16(ah[ks], blv, C[ct], 0, 0, 0);
      }
    }
    if (rt < 3){
      #pragma unroll
      for (int ct = 0; ct < 4; ++ct)
        #pragma unroll
        for (int r = 0; r < 4; ++r) m4[ct] = fmaxf(m4[ct], C[ct][r]);
    } else {
      if (quad == 0){
        #pragma unroll
        for (int ct = 0; ct < 4; ++ct){
          m4[ct] = fmaxf(m4[ct], C[ct][0]);
          m4[ct] = fmaxf(m4[ct], C[ct][1]);
        }
      }
    }
  }
  #pragma unroll
  for (int ct = 0; ct < 4; ++ct){
    m4[ct] = fmaxf(m4[ct], __shfl_xor(m4[ct], 16));
    m4[ct] = fmaxf(m4[ct], __shfl_xor(m4[ct], 32));
  }
  if (quad == 0){
    #pragma unroll
    for (int ct = 0; ct < 4; ++ct){
      int o = ct*16 + nl;
      cin[(size_t)gq*64 + o] = leaky(m4[ct] + bb2[o]);
    }
  }
}

// ---------------- downsample conv (1,3) stride (1,2) pad (0,1) ----------------
__global__ __launch_bounds__(256) void k_down(const float* __restrict__ cin,
                                              const float* __restrict__ wdt,
                                              const float* __restrict__ bias,
                                              float* __restrict__ outp){
  int blk = blockIdx.x;
  int b = blk >> 8, r = blk & 255, s = r >> 3, oq = r & 7;
  int t = threadIdx.x;
  __shared__ __align__(16) float L[34*68];
  for (int k = t; k < 34*64; k += 256){
    int rr = k >> 6, i = k & 63;
    int pp = oq*32 - 1 + rr;
    float v = 0.f;
    if (pp >= 0 && pp < 256) v = cin[(size_t)(b*8192 + s*256 + pp)*64 + i];
    L[rr*68 + i] = v;
  }
  __syncthreads();
  #pragma unroll
  for (int kk = 0; kk < 4; ++kk){
    int ow = kk*256 + t;
    int o = ow >> 4, wl = ow & 15;
    float acc = bias[o];
    #pragma unroll
    for (int tt = 0; tt < 3; ++tt){
      int rr = 2*wl + tt;
      const float4* lv4 = (const float4*)(L + rr*68);
      const float4* wv4 = (const float4*)(wdt + tt*4096 + o*64);
      #pragma unroll
      for (int i4 = 0; i4 < 16; ++i4){
        float4 lv = lv4[i4], wv = wv4[i4];
        acc += wv.x*lv.x + wv.y*lv.y + wv.z*lv.z + wv.w*lv.w;
      }
    }
    int w_ = oq*16 + wl;
    outp[16384 + (size_t)((b*64 + o)*32 + s)*128 + w_] = leaky(acc);
  }
}

extern "C" void kernel_launch(void* const* d_in, const int* in_sizes, int n_in,
                              void* d_out, int out_size, void* d_ws, size_t ws_size,
                              hipStream_t stream){
  (void)in_sizes; (void)n_in; (void)out_size; (void)ws_size;
  const float* sparse = (const float*)d_in[0];
  const float* dense  = (const float*)d_in[1];
  const float* spW1   = (const float*)d_in[2];
  const float* spb1   = (const float*)d_in[3];
  const float* spW2   = (const float*)d_in[4];
  const float* spb2   = (const float*)d_in[5];
  const float* dnW1   = (const float*)d_in[6];
  const float* dnb1   = (const float*)d_in[7];
  const float* dnW2   = (const float*)d_in[8];
  const float* dnb2   = (const float*)d_in[9];
  const float* dsW    = (const float*)d_in[10];
  const float* dsb    = (const float*)d_in[11];
  float* out = (float*)d_out;

  float* w    = (float*)d_ws;                  // 63.5 MB
  float* xt   = w;                             // 3,145,728
  float* x2   = w + 3145728;                   //    32,768
  float* g1   = w + 3178496;                   // 3,670,016 (stride 112)
  float* p1   = w + 6848512;                   // 3,670,016
  int*   i50  = (int*)(w + 10518528);          // 1,638,400
  float* cin  = w + 12156928;                  // 2,097,152
  float* xtsp = w + 14254080;                  //    12,288
  unsigned short* xtb = (unsigned short*)(w + 14266368);  // 3,145,728 u16
  unsigned short* w1h = (unsigned short*)(w + 15839232);  // 21504 u16
  unsigned short* w1l = (unsigned short*)(w + 15849984);
  unsigned short* w2h = (unsigned short*)(w + 15860736);  // 8192 u16
  unsigned short* w2l = (unsigned short*)(w + 15864832);
  float* wdt  = w + 15868928;                  // 12,288

  k_stage1<<<804,  256, 0, stream>>>(dense, sparse, dnW1, dnW2, dsW,
                                     xt, xtb, x2, xtsp, w1h, w1l, w2h, w2l, wdt);
  k_stage2<<<1152, 256, 0, stream>>>(xtb, x2, xt, i50, w1h, w1l, dnb1, g1, p1,
                                     xtsp, spW1, spb1, spW2, spb2, out);
  k_econv <<<4096, 512, 0, stream>>>(g1, p1, i50, w2h, w2l, dnb2, cin);
  k_down  <<<1024, 256, 0, stream>>>(cin, wdt, dsb, out);
}